// Round 4
// baseline (95.214 us; speedup 1.0000x reference)
//
#include <hip/hip_runtime.h>

// MoE all-experts dense MLP, fused bf16-MFMA kernel.
// E=8, D_IN=128, D_HID=256, D_OUT=128, B=65536. Out f32 [B,128].
// Structure: M=64 rows/wave, 2 waves/block (BM=128), grid=512 (2 blocks/CU).
// Weights prepacked into chunk-major, inverse-swizzled bf16 records (Wall);
// b1 folded in via rank-1 MFMA; all LDS addresses precomputed.

#define E_    8
#define DIN_  128
#define DH_   256
#define DOUT_ 128
#define BM_   128
#define NCHUNK 32
#define RECSZ 34816   // 16K W1c + 16K W2c + 2K b1 region

typedef __attribute__((ext_vector_type(8))) short bf16x8;
typedef __attribute__((ext_vector_type(16))) float f32x16;
typedef __attribute__((ext_vector_type(2))) unsigned int uint2v;

__device__ __forceinline__ unsigned short f2bf(float f) {
  union { float f; unsigned int u; } v; v.f = f;
  unsigned int u = v.u;
  u += 0x7fffu + ((u >> 16) & 1u);
  return (unsigned short)(u >> 16);
}

__device__ __forceinline__ unsigned int cvt_pk_bf16(float lo, float hi) {
  unsigned int r;
  asm("v_cvt_pk_bf16_f32 %0, %1, %2" : "=v"(r) : "v"(lo), "v"(hi));
  return r;
}

__device__ __forceinline__ bf16x8 pack4(unsigned int a, unsigned int b,
                                        unsigned int c, unsigned int d) {
  union { unsigned int u[4]; bf16x8 v; } t;
  t.u[0] = a; t.u[1] = b; t.u[2] = c; t.u[3] = d;
  return t.v;
}

__device__ __forceinline__ void gload_lds16(const void* g, void* l) {
  __builtin_amdgcn_global_load_lds(
      (const __attribute__((address_space(1))) unsigned int*)g,
      (__attribute__((address_space(3))) unsigned int*)l, 16, 0, 0);
}

// ---------------- prep: build Wall[32][RECSZ] ----------------
// Record t (e=t>>2, hc=t&3):
//  [0,16K):  W1c rows c=0..63 (256B: k-bytes), stored so that
//            rec[c*256+u] = W1bf16bytes[c][u ^ ((c&7)<<4)]
//  [16K,32K): W2c rows n=0..127 (128B: c-bytes), rec[16K+n*128+u] =
//            W2bf16bytes[n][u ^ ((n&7)<<4)]
//  [32K,34K): b1 rows c=0..63, 32B each: [bf16 b1, zeros]
__global__ __launch_bounds__(256) void prep_pack(
    const float* __restrict__ W1, const float* __restrict__ W2,
    const float* __restrict__ b1, unsigned char* __restrict__ Wall)
{
  __shared__ float T[8192];
  const int bid = blockIdx.x;
  const int t = bid >> 1, region = bid & 1;
  const int e = t >> 2, hc = t & 3;
  const int tid = threadIdx.x;
  unsigned char* rec = Wall + (size_t)t * RECSZ;

  if (region == 0) {
    // T[k*64+c] = W1[e][k][hc*64+c]   (W1: [E][DIN][DH])
    #pragma unroll
    for (int i = 0; i < 32; ++i) {
      int idx = i * 256 + tid;
      int k = idx >> 6, c = idx & 63;
      T[idx] = W1[((size_t)(e * DIN_ + k)) * DH_ + hc * 64 + c];
    }
    __syncthreads();
    #pragma unroll
    for (int j = 0; j < 16; ++j) {
      int widx = j * 256 + tid;              // 4096 words
      int c = widx >> 6, uw = (widx & 63) * 4;
      int up = uw ^ ((c & 7) << 4);
      int k0 = up >> 1;                      // even
      unsigned int val = (unsigned int)f2bf(T[k0 * 64 + c]) |
                         ((unsigned int)f2bf(T[(k0 + 1) * 64 + c]) << 16);
      *(unsigned int*)(rec + c * 256 + uw) = val;
    }
    if (tid < 64) {
      *(unsigned int*)(rec + 32768 + tid * 32) =
          (unsigned int)f2bf(b1[e * DH_ + hc * 64 + tid]);
      #pragma unroll
      for (int p = 1; p < 8; ++p)
        *(unsigned int*)(rec + 32768 + tid * 32 + p * 4) = 0u;
    }
  } else {
    // T[h*128+n] = W2[e][hc*64+h][n]   (W2: [E][DH][DOUT])
    #pragma unroll
    for (int i = 0; i < 32; ++i) {
      int idx = i * 256 + tid;
      int h = idx >> 7, n = idx & 127;
      T[idx] = W2[((size_t)(e * DH_ + hc * 64 + h)) * DOUT_ + n];
    }
    __syncthreads();
    #pragma unroll
    for (int j = 0; j < 16; ++j) {
      int widx = j * 256 + tid;
      int n = widx >> 5, uw = (widx & 31) * 4;
      int up = uw ^ ((n & 7) << 4);
      int h0 = up >> 1;
      unsigned int val = (unsigned int)f2bf(T[h0 * 128 + n]) |
                         ((unsigned int)f2bf(T[(h0 + 1) * 128 + n]) << 16);
      *(unsigned int*)(rec + 16384 + n * 128 + uw) = val;
    }
  }
}

// ---------------- main fused kernel ----------------
__global__ __launch_bounds__(128, 1) void moe_main(
    const float* __restrict__ x, const float* __restrict__ wts,
    const float* __restrict__ b2, const unsigned char* __restrict__ Wall,
    float* __restrict__ out)
{
  __shared__ __align__(16) unsigned char L[2][RECSZ];   // 68 KB dbuf

  const int tid  = threadIdx.x;
  const int lane = tid & 63;
  const int wv   = tid >> 6;        // 0..1
  const int l32  = lane & 31;
  const int hi   = lane >> 5;
  const int swz  = (l32 & 7) << 4;
  const long bm  = (long)blockIdx.x * BM_;
  const long row0 = bm + wv * 64 + l32;    // mt=0 row; mt=1 is +32

  auto stage = [&](int t, unsigned char* dst) {
    const unsigned char* src = Wall + (size_t)t * RECSZ;
    #pragma unroll
    for (int r = 0; r < 17; ++r)
      gload_lds16(src + (r * 128 + tid) * 16, dst + r * 2048 + wv * 1024);
  };

  stage(0, L[0]);

  // precomputed LDS offsets (XOR folded; loop carries only immediates)
  int p1o[8], p2o[4];
  #pragma unroll
  for (int ks = 0; ks < 8; ++ks)
    p1o[ks] = l32 * 256 + ((ks * 32 + hi * 16) ^ swz);
  #pragma unroll
  for (int k2 = 0; k2 < 4; ++k2)
    p2o[k2] = 16384 + l32 * 128 + ((k2 * 32 + hi * 16) ^ swz);
  const int bo = 32768 + l32 * 32 + hi * 16;

  const bf16x8 ones = pack4(hi ? 0u : 0x3F80u, 0u, 0u, 0u);

  // x fragments: xf[mt][ks], col=m=l32 within tile, k = ks*16 + hi*8 + j
  bf16x8 xf[2][8];
  #pragma unroll
  for (int mt = 0; mt < 2; ++mt) {
    const float* xr0 = x + (row0 + mt * 32) * DIN_;
    #pragma unroll
    for (int ks = 0; ks < 8; ++ks) {
      const float* xr = xr0 + ks * 16 + hi * 8;
      float4 a = *(const float4*)xr;
      float4 b = *(const float4*)(xr + 4);
      xf[mt][ks] = pack4(cvt_pk_bf16(a.x, a.y), cvt_pk_bf16(a.z, a.w),
                         cvt_pk_bf16(b.x, b.y), cvt_pk_bf16(b.z, b.w));
    }
  }

  const float* wp0 = wts + row0 * E_;          // expert weights, row mt=0
  const float* wp1 = wts + (row0 + 32) * E_;   // row mt=1

  f32x16 oacc[2][4];   // [mt][nf]; D col=n=nf*32+l32, rows reg-mapped
  #pragma unroll
  for (int mt = 0; mt < 2; ++mt)
    #pragma unroll
    for (int nf = 0; nf < 4; ++nf) oacc[mt][nf] = 0.0f;

  auto chunk = [&](const unsigned char* Lb, int t) {
    const int e = t >> 2;
    const float wA = wp0[e], wB = wp1[e];   // issued early, used at repack

    // ---- phase 1: H^T, c=64, K=128; A-frag shared across both m-tiles
    f32x16 h[2][2];   // [cf][mt]
    h[0][0] = 0.0f; h[0][1] = 0.0f; h[1][0] = 0.0f; h[1][1] = 0.0f;
    #pragma unroll
    for (int ks = 0; ks < 8; ++ks) {
      bf16x8 a0 = *(const bf16x8*)(Lb + p1o[ks]);
      bf16x8 a1 = *(const bf16x8*)(Lb + p1o[ks] + 8192);
      h[0][0] = __builtin_amdgcn_mfma_f32_32x32x16_bf16(a0, xf[0][ks], h[0][0], 0, 0, 0);
      h[0][1] = __builtin_amdgcn_mfma_f32_32x32x16_bf16(a0, xf[1][ks], h[0][1], 0, 0, 0);
      h[1][0] = __builtin_amdgcn_mfma_f32_32x32x16_bf16(a1, xf[0][ks], h[1][0], 0, 0, 0);
      h[1][1] = __builtin_amdgcn_mfma_f32_32x32x16_bf16(a1, xf[1][ks], h[1][1], 0, 0, 0);
    }
    // bias via rank-1 MFMA: A=b1frag (nonzero only k=0), B=ones (1.0 at k=0)
    {
      bf16x8 bf0 = *(const bf16x8*)(Lb + bo);
      bf16x8 bf1 = *(const bf16x8*)(Lb + bo + 1024);
      h[0][0] = __builtin_amdgcn_mfma_f32_32x32x16_bf16(bf0, ones, h[0][0], 0, 0, 0);
      h[0][1] = __builtin_amdgcn_mfma_f32_32x32x16_bf16(bf0, ones, h[0][1], 0, 0, 0);
      h[1][0] = __builtin_amdgcn_mfma_f32_32x32x16_bf16(bf1, ones, h[1][0], 0, 0, 0);
      h[1][1] = __builtin_amdgcn_mfma_f32_32x32x16_bf16(bf1, ones, h[1][1], 0, 0, 0);
    }

    // ---- relu + fold w; cvt_pk + permlane32_swap -> phase-2 A-frags (T12)
    bf16x8 hfr[2][4];   // [mt][ks2]
    #pragma unroll
    for (int mt = 0; mt < 2; ++mt) {
      const float w = mt ? wB : wA;
      #pragma unroll
      for (int cf = 0; cf < 2; ++cf) {
        unsigned int u[8];
        #pragma unroll
        for (int p = 0; p < 8; ++p) {
          float h0 = fmaxf(h[cf][mt][2 * p],     0.0f) * w;
          float h1 = fmaxf(h[cf][mt][2 * p + 1], 0.0f) * w;
          u[p] = cvt_pk_bf16(h0, h1);
        }
        uint2v s02 = __builtin_amdgcn_permlane32_swap(u[0], u[2], false, false);
        uint2v s13 = __builtin_amdgcn_permlane32_swap(u[1], u[3], false, false);
        uint2v s46 = __builtin_amdgcn_permlane32_swap(u[4], u[6], false, false);
        uint2v s57 = __builtin_amdgcn_permlane32_swap(u[5], u[7], false, false);
        hfr[mt][2 * cf]     = pack4(s02[0], s13[0], s02[1], s13[1]);
        hfr[mt][2 * cf + 1] = pack4(s46[0], s57[0], s46[1], s57[1]);
      }
    }

    // ---- phase 2: out += H * W2c; B-frag shared across both m-tiles
    #pragma unroll
    for (int k2 = 0; k2 < 4; ++k2) {
      #pragma unroll
      for (int nf = 0; nf < 4; ++nf) {
        bf16x8 b = *(const bf16x8*)(Lb + p2o[k2] + nf * 4096);
        oacc[0][nf] = __builtin_amdgcn_mfma_f32_32x32x16_bf16(hfr[0][k2], b, oacc[0][nf], 0, 0, 0);
        oacc[1][nf] = __builtin_amdgcn_mfma_f32_32x32x16_bf16(hfr[1][k2], b, oacc[1][nf], 0, 0, 0);
      }
    }
  };

  for (int tt = 0; tt < NCHUNK; tt += 2) {
    __syncthreads();                       // L[0] staged; L[1] free
    if (tt + 1 < NCHUNK) stage(tt + 1, L[1]);
    chunk(L[0], tt);
    __syncthreads();                       // L[1] staged; L[0] free
    if (tt + 2 < NCHUNK) stage(tt + 2, L[0]);
    chunk(L[1], tt + 1);
  }

  // ---- epilogue: fold Sigma_e w[m][e]*b2[e][n] via one rank-8 MFMA per frag
  const unsigned int z = 0;
  float wv0[8], wv1[8];
  {
    float4 a = *(const float4*)wp0; float4 b = *(const float4*)(wp0 + 4);
    wv0[0]=a.x; wv0[1]=a.y; wv0[2]=a.z; wv0[3]=a.w;
    wv0[4]=b.x; wv0[5]=b.y; wv0[6]=b.z; wv0[7]=b.w;
    float4 c = *(const float4*)wp1; float4 d = *(const float4*)(wp1 + 4);
    wv1[0]=c.x; wv1[1]=c.y; wv1[2]=c.z; wv1[3]=c.w;
    wv1[4]=d.x; wv1[5]=d.y; wv1[6]=d.z; wv1[7]=d.w;
  }
  bf16x8 wfrag[2];
  wfrag[0] = pack4(hi ? z : cvt_pk_bf16(wv0[0], wv0[1]),
                   hi ? z : cvt_pk_bf16(wv0[2], wv0[3]),
                   hi ? z : cvt_pk_bf16(wv0[4], wv0[5]),
                   hi ? z : cvt_pk_bf16(wv0[6], wv0[7]));
  wfrag[1] = pack4(hi ? z : cvt_pk_bf16(wv1[0], wv1[1]),
                   hi ? z : cvt_pk_bf16(wv1[2], wv1[3]),
                   hi ? z : cvt_pk_bf16(wv1[4], wv1[5]),
                   hi ? z : cvt_pk_bf16(wv1[6], wv1[7]));
  #pragma unroll
  for (int nf = 0; nf < 4; ++nf) {
    const float* bp = b2 + nf * 32 + l32;
    bf16x8 bfrag = pack4(
        hi ? z : cvt_pk_bf16(bp[0 * DOUT_], bp[1 * DOUT_]),
        hi ? z : cvt_pk_bf16(bp[2 * DOUT_], bp[3 * DOUT_]),
        hi ? z : cvt_pk_bf16(bp[4 * DOUT_], bp[5 * DOUT_]),
        hi ? z : cvt_pk_bf16(bp[6 * DOUT_], bp[7 * DOUT_]));
    oacc[0][nf] = __builtin_amdgcn_mfma_f32_32x32x16_bf16(wfrag[0], bfrag, oacc[0][nf], 0, 0, 0);
    oacc[1][nf] = __builtin_amdgcn_mfma_f32_32x32x16_bf16(wfrag[1], bfrag, oacc[1][nf], 0, 0, 0);
  }

  // ---- store
  #pragma unroll
  for (int mt = 0; mt < 2; ++mt) {
    #pragma unroll
    for (int nf = 0; nf < 4; ++nf) {
      #pragma unroll
      for (int r = 0; r < 16; ++r) {
        const int mloc = (r & 3) + 8 * (r >> 2) + 4 * hi;
        out[(bm + wv * 64 + mt * 32 + mloc) * DOUT_ + nf * 32 + l32] =
            oacc[mt][nf][r];
      }
    }
  }
}

extern "C" void kernel_launch(void* const* d_in, const int* in_sizes, int n_in,
                              void* d_out, int out_size, void* d_ws, size_t ws_size,
                              hipStream_t stream) {
  const float* x   = (const float*)d_in[0];
  const float* wts = (const float*)d_in[1];
  const float* W1  = (const float*)d_in[2];
  const float* b1  = (const float*)d_in[3];
  const float* W2  = (const float*)d_in[4];
  const float* b2  = (const float*)d_in[5];
  float* out = (float*)d_out;

  unsigned char* Wall = (unsigned char*)d_ws;   // 32 * 34816 = 1.06 MB

  prep_pack<<<64, 256, 0, stream>>>(W1, W2, b1, Wall);
  moe_main<<<65536 / BM_, 128, 0, stream>>>(x, wts, b2, Wall, out);
}